// Round 6
// baseline (279.928 us; speedup 1.0000x reference)
//
#include <hip/hip_runtime.h>
#include <math.h>

// out[i][j] = | prod_w cos((x[i][w]+y[j][w])/2 + theta[w]) |
//           = | prod_w ( cos(ax_w)cos(ay_w) - sin(ax_w)sin(ay_w) ) |
// (RX(x)RX(th)=RX(x+th); CNOT ladder = basis permutation, cancels in the plain
//  bilinear form; inner product factorizes per wire.)
//
// R6: "linear-sweep" store schedule. Global wave W of NW=8192 writes 1 KiB chunk
// C = k*NW + W at step k — identical temporal pattern to the 6.5 TB/s harness
// fill (all waves inside one contiguous 8 MiB window sliding over the output),
// instead of the 2D-tiled pattern that keeps all 256 MiB active (row-buffer
// thrash, ~2.8 TB/s). Chunk->(i,j): i = C/(By/256), jc = C%(By/256); per wave
// jc is FIXED (B-trig in regs once), i advances by 256/step (4 sincos/step).

#define BM 16
#define BN 256
#define TJ 8
#define NWAVES 8192          // 2048 blocks x 4 waves

typedef float floatx4 __attribute__((ext_vector_type(4)));

// ---------------- R6 main: linear-sweep writer ----------------
__global__ __launch_bounds__(256) void qk_sweep(
    const float* __restrict__ x, const float* __restrict__ y,
    const float* __restrict__ theta, float* __restrict__ out,
    int Bx, int By, int steps)
{
    const int tid  = threadIdx.x;
    const int lane = tid & 63;
    const int wid  = (blockIdx.x << 2) + (tid >> 6);   // global wave id, 0..NWAVES-1
    const int cpr  = By >> 8;                          // 1 KiB chunks per row (=32)
    const int jc   = wid % cpr;                        // fixed column panel
    const int i0   = wid / cpr;                        // first row
    const int di   = NWAVES / cpr;                     // row advance per step (=256)
    const int col0 = jc * 256 + lane * 4;

    const float th0 = 0.5f * theta[0], th1 = 0.5f * theta[1];
    const float th2 = 0.5f * theta[2], th3 = 0.5f * theta[3];

    // B-side trig: this lane's 4 columns, computed once, lives in regs.
    float cb[4][4], sb[4][4];          // [wire][col]
    #pragma unroll
    for (int jj = 0; jj < 4; ++jj) {
        const float4 y4 = ((const float4*)y)[col0 + jj];
        __sincosf(0.5f * y4.x + th0, &sb[0][jj], &cb[0][jj]);
        __sincosf(0.5f * y4.y + th1, &sb[1][jj], &cb[1][jj]);
        __sincosf(0.5f * y4.z + th2, &sb[2][jj], &cb[2][jj]);
        __sincosf(0.5f * y4.w + th3, &sb[3][jj], &cb[3][jj]);
    }

    // Rolling prefetch of the wave-uniform x row.
    float4 xc = ((const float4*)x)[i0];
    size_t chunk = (size_t)wid;                        // chunk index = k*NWAVES + wid

    for (int k = 0; k < steps; ++k) {
        float4 xn;
        if (k + 1 < steps) xn = ((const float4*)x)[i0 + (k + 1) * di];

        // A-side trig for row i(k): 4 sincos (wave-uniform values).
        float caw[4], saw[4];
        __sincosf(0.5f * xc.x + th0, &saw[0], &caw[0]);
        __sincosf(0.5f * xc.y + th1, &saw[1], &caw[1]);
        __sincosf(0.5f * xc.z + th2, &saw[2], &caw[2]);
        __sincosf(0.5f * xc.w + th3, &saw[3], &caw[3]);

        floatx4 o;
        #pragma unroll
        for (int jj = 0; jj < 4; ++jj) {
            const float t0 = fmaf(caw[0], cb[0][jj], -(saw[0] * sb[0][jj]));
            const float t1 = fmaf(caw[1], cb[1][jj], -(saw[1] * sb[1][jj]));
            const float t2 = fmaf(caw[2], cb[2][jj], -(saw[2] * sb[2][jj]));
            const float t3 = fmaf(caw[3], cb[3][jj], -(saw[3] * sb[3][jj]));
            o[jj] = fabsf((t0 * t1) * (t2 * t3));
        }

        // One coalesced 1 KiB wave-store; chip-wide step-k addresses form one
        // contiguous 8 MiB window (fill-like linear sweep).
        *(floatx4*)&out[chunk * 256 + (size_t)(lane * 4)] = o;

        chunk += NWAVES;
        xc = xn;
    }
}

// ---------------- prior streaming kernel (plain stores) ----------------
__global__ __launch_bounds__(256) void qk_stream(
    const float* __restrict__ x, const float* __restrict__ y,
    const float* __restrict__ theta, float* __restrict__ out,
    int Nx, int Ny)
{
    const int tid = threadIdx.x;
    const int tx = tid & 63;
    const int ty = tid >> 6;
    const int i0 = blockIdx.y * BM;
    const int j0 = blockIdx.x * (BN * TJ);
    const int r0 = i0 + ty * 4;

    const float th0 = 0.5f * theta[0], th1 = 0.5f * theta[1];
    const float th2 = 0.5f * theta[2], th3 = 0.5f * theta[3];

    float ca[4][4], sa[4][4];
    #pragma unroll
    for (int i = 0; i < 4; ++i) {
        const float4 x4 = ((const float4*)x)[r0 + i];
        __sincosf(0.5f * x4.x + th0, &sa[0][i], &ca[0][i]);
        __sincosf(0.5f * x4.y + th1, &sa[1][i], &ca[1][i]);
        __sincosf(0.5f * x4.z + th2, &sa[2][i], &ca[2][i]);
        __sincosf(0.5f * x4.w + th3, &sa[3][i], &ca[3][i]);
    }

    #pragma unroll 2
    for (int t = 0; t < TJ; ++t) {
        const int j = j0 + t * BN + tx * 4;

        float cb[4][4], sb[4][4];
        #pragma unroll
        for (int jj = 0; jj < 4; ++jj) {
            const float4 y4 = ((const float4*)y)[j + jj];
            __sincosf(0.5f * y4.x + th0, &sb[0][jj], &cb[0][jj]);
            __sincosf(0.5f * y4.y + th1, &sb[1][jj], &cb[1][jj]);
            __sincosf(0.5f * y4.z + th2, &sb[2][jj], &cb[2][jj]);
            __sincosf(0.5f * y4.w + th3, &sb[3][jj], &cb[3][jj]);
        }

        float acc[4][4];
        #pragma unroll
        for (int i = 0; i < 4; ++i) {
            #pragma unroll
            for (int jj = 0; jj < 4; ++jj) {
                const float t0 = fmaf(ca[0][i], cb[0][jj], -(sa[0][i] * sb[0][jj]));
                const float t1 = fmaf(ca[1][i], cb[1][jj], -(sa[1][i] * sb[1][jj]));
                const float t2 = fmaf(ca[2][i], cb[2][jj], -(sa[2][i] * sb[2][jj]));
                const float t3 = fmaf(ca[3][i], cb[3][jj], -(sa[3][i] * sb[3][jj]));
                acc[i][jj] = fabsf((t0 * t1) * (t2 * t3));
            }
        }

        #pragma unroll
        for (int i = 0; i < 4; ++i) {
            float4 o;
            o.x = acc[i][0]; o.y = acc[i][1]; o.z = acc[i][2]; o.w = acc[i][3];
            *(float4*)&out[(size_t)(r0 + i) * Ny + j] = o;
        }
    }
}

extern "C" void kernel_launch(void* const* d_in, const int* in_sizes, int n_in,
                              void* d_out, int out_size, void* d_ws, size_t ws_size,
                              hipStream_t stream) {
    (void)n_in; (void)out_size; (void)d_ws; (void)ws_size;
    const float* x     = (const float*)d_in[0];
    const float* y     = (const float*)d_in[1];
    const float* theta = (const float*)d_in[2];
    float* out = (float*)d_out;

    const int Bx = in_sizes[0] / 4;  // 8192
    const int By = in_sizes[1] / 4;  // 8192

    // Linear-sweep guards: whole rows decompose into 1 KiB chunks, wave count
    // divides total chunks, and each wave keeps a fixed column panel.
    if ((By % 256) == 0) {
        const int cpr = By >> 8;
        const long long chunks = (long long)Bx * cpr;
        if ((NWAVES % cpr) == 0 && (chunks % NWAVES) == 0 && (By % 1024) == 0) {
            const int steps = (int)(chunks / NWAVES);
            qk_sweep<<<dim3(NWAVES / 4), dim3(256), 0, stream>>>(
                x, y, theta, out, Bx, By, steps);
            return;
        }
    }
    if ((By % (BN * TJ)) == 0 && (Bx % BM) == 0) {
        dim3 grid(By / (BN * TJ), Bx / BM);
        qk_stream<<<grid, dim3(256), 0, stream>>>(x, y, theta, out, Bx, By);
        return;
    }
    // Last resort: minimal per-element kernel not needed — shapes are fixed by
    // the harness (8192x8192); qk_stream covers all multiples of (2048,16).
    dim3 grid(By / BN, Bx / BM);
    qk_stream<<<grid, dim3(256), 0, stream>>>(x, y, theta, out, Bx, By);
}

// Round 7
// 257.322 us; speedup vs baseline: 1.0878x; 1.0878x over previous
//
#include <hip/hip_runtime.h>
#include <math.h>

// out[i][j] = | prod_w cos((x[i][w]+y[j][w])/2 + theta[w]) |
//           = | prod_w ( cos(ax_w)cos(ay_w) - sin(ax_w)sin(ay_w) ) |
// (RX(x)RX(th)=RX(x+th); CNOT ladder = basis permutation, cancels in the plain
//  bilinear form; inner product factorizes per wire.)
//
// R7 "persistent panel": block = 256-col x 128-row output panel. ALL global
// loads + trig happen before the first store (LDS-staged); the row loop does
// only LDS-broadcast reads (lgkmcnt) + VALU + one contiguous 1 KiB wave-store.
// Rationale: loads and stores share the in-order vmcnt queue -> any load after
// a store waits for ALL prior stores to drain (R6's regression); the 6.6 TB/s
// fill kernel has zero loads. This kernel has zero vmem loads in store phase.

#define PBM 128   // rows per block
#define PBN 256   // cols per block
#define BM 16     // fallback tile
#define BN 256
#define TJ 8

typedef float floatx4 __attribute__((ext_vector_type(4)));

// ---------------- R7 main: persistent-panel writer ----------------
__global__ __launch_bounds__(256) void qk_persist(
    const float* __restrict__ x, const float* __restrict__ y,
    const float* __restrict__ theta, float* __restrict__ out,
    int Bx, int By)
{
    __shared__ float at[8][PBM];   // A trig: [0..3]=cos,[4..7]=sin per wire
    __shared__ float bt[8][PBN];   // B trig

    const int tid  = threadIdx.x;
    const int nPan = By >> 8;                 // column panels (=32)
    const int jc   = blockIdx.x % nPan;       // this block's column panel
    const int r0   = (blockIdx.x / nPan) * PBM;

    const float th0 = 0.5f * theta[0], th1 = 0.5f * theta[1];
    const float th2 = 0.5f * theta[2], th3 = 0.5f * theta[3];

    // Stage B trig: one y-row per thread (coalesced float4).
    {
        const float4 y4 = ((const float4*)y)[jc * PBN + tid];
        float s, c;
        __sincosf(0.5f * y4.x + th0, &s, &c); bt[0][tid] = c; bt[4][tid] = s;
        __sincosf(0.5f * y4.y + th1, &s, &c); bt[1][tid] = c; bt[5][tid] = s;
        __sincosf(0.5f * y4.z + th2, &s, &c); bt[2][tid] = c; bt[6][tid] = s;
        __sincosf(0.5f * y4.w + th3, &s, &c); bt[3][tid] = c; bt[7][tid] = s;
    }
    // Stage A trig: 128 x-rows, threads 0..127.
    if (tid < PBM) {
        const float4 x4 = ((const float4*)x)[r0 + tid];
        float s, c;
        __sincosf(0.5f * x4.x + th0, &s, &c); at[0][tid] = c; at[4][tid] = s;
        __sincosf(0.5f * x4.y + th1, &s, &c); at[1][tid] = c; at[5][tid] = s;
        __sincosf(0.5f * x4.z + th2, &s, &c); at[2][tid] = c; at[6][tid] = s;
        __sincosf(0.5f * x4.w + th3, &s, &c); at[3][tid] = c; at[7][tid] = s;
    }
    __syncthreads();

    const int lane = tid & 63;
    const int ty   = tid >> 6;

    // Hoist this lane's 4-column B fragments into registers (loop-invariant).
    // ds_read_b128, lane stride 16 B -> all 32 banks, conflict-free.
    float cbj[4][4], sbj[4][4];    // [wire][col]
    #pragma unroll
    for (int w = 0; w < 4; ++w) {
        const float4 c4 = ((const float4*)&bt[w][0])[lane];
        const float4 s4 = ((const float4*)&bt[w + 4][0])[lane];
        cbj[w][0] = c4.x; cbj[w][1] = c4.y; cbj[w][2] = c4.z; cbj[w][3] = c4.w;
        sbj[w][0] = s4.x; sbj[w][1] = s4.y; sbj[w][2] = s4.z; sbj[w][3] = s4.w;
    }

    const size_t colBase = (size_t)jc * PBN + (size_t)(lane * 4);

    // Row loop: 8 LDS broadcasts + ~50 VALU + one 1 KiB contiguous wave-store.
    // Zero vmem loads here -> stores are never drained by a waitcnt.
    #pragma unroll 2
    for (int it = 0; it < PBM / 4; ++it) {
        const int r = it * 4 + ty;             // wave-uniform local row

        float caw[4], saw[4];
        #pragma unroll
        for (int w = 0; w < 4; ++w) {          // broadcast reads (same addr/wave)
            caw[w] = at[w][r];
            saw[w] = at[w + 4][r];
        }

        floatx4 o;
        #pragma unroll
        for (int jj = 0; jj < 4; ++jj) {
            const float t0 = fmaf(caw[0], cbj[0][jj], -(saw[0] * sbj[0][jj]));
            const float t1 = fmaf(caw[1], cbj[1][jj], -(saw[1] * sbj[1][jj]));
            const float t2 = fmaf(caw[2], cbj[2][jj], -(saw[2] * sbj[2][jj]));
            const float t3 = fmaf(caw[3], cbj[3][jj], -(saw[3] * sbj[3][jj]));
            o[jj] = fabsf((t0 * t1) * (t2 * t3));
        }

        *(floatx4*)&out[(size_t)(r0 + r) * By + colBase] = o;
    }
}

// ---------------- fallback: R3 streaming kernel ----------------
__global__ __launch_bounds__(256) void qk_stream(
    const float* __restrict__ x, const float* __restrict__ y,
    const float* __restrict__ theta, float* __restrict__ out,
    int Nx, int Ny)
{
    const int tid = threadIdx.x;
    const int tx = tid & 63;
    const int ty = tid >> 6;
    const int i0 = blockIdx.y * BM;
    const int j0 = blockIdx.x * (BN * TJ);
    const int r0 = i0 + ty * 4;

    const float th0 = 0.5f * theta[0], th1 = 0.5f * theta[1];
    const float th2 = 0.5f * theta[2], th3 = 0.5f * theta[3];

    float ca[4][4], sa[4][4];
    #pragma unroll
    for (int i = 0; i < 4; ++i) {
        const float4 x4 = ((const float4*)x)[r0 + i];
        __sincosf(0.5f * x4.x + th0, &sa[0][i], &ca[0][i]);
        __sincosf(0.5f * x4.y + th1, &sa[1][i], &ca[1][i]);
        __sincosf(0.5f * x4.z + th2, &sa[2][i], &ca[2][i]);
        __sincosf(0.5f * x4.w + th3, &sa[3][i], &ca[3][i]);
    }

    #pragma unroll 2
    for (int t = 0; t < TJ; ++t) {
        const int j = j0 + t * BN + tx * 4;

        float cb[4][4], sb[4][4];
        #pragma unroll
        for (int jj = 0; jj < 4; ++jj) {
            const float4 y4 = ((const float4*)y)[j + jj];
            __sincosf(0.5f * y4.x + th0, &sb[0][jj], &cb[0][jj]);
            __sincosf(0.5f * y4.y + th1, &sb[1][jj], &cb[1][jj]);
            __sincosf(0.5f * y4.z + th2, &sb[2][jj], &cb[2][jj]);
            __sincosf(0.5f * y4.w + th3, &sb[3][jj], &cb[3][jj]);
        }

        float acc[4][4];
        #pragma unroll
        for (int i = 0; i < 4; ++i) {
            #pragma unroll
            for (int jj = 0; jj < 4; ++jj) {
                const float t0 = fmaf(ca[0][i], cb[0][jj], -(sa[0][i] * sb[0][jj]));
                const float t1 = fmaf(ca[1][i], cb[1][jj], -(sa[1][i] * sb[1][jj]));
                const float t2 = fmaf(ca[2][i], cb[2][jj], -(sa[2][i] * sb[2][jj]));
                const float t3 = fmaf(ca[3][i], cb[3][jj], -(sa[3][i] * sb[3][jj]));
                acc[i][jj] = fabsf((t0 * t1) * (t2 * t3));
            }
        }

        #pragma unroll
        for (int i = 0; i < 4; ++i) {
            float4 o;
            o.x = acc[i][0]; o.y = acc[i][1]; o.z = acc[i][2]; o.w = acc[i][3];
            *(float4*)&out[(size_t)(r0 + i) * Ny + j] = o;
        }
    }
}

extern "C" void kernel_launch(void* const* d_in, const int* in_sizes, int n_in,
                              void* d_out, int out_size, void* d_ws, size_t ws_size,
                              hipStream_t stream) {
    (void)n_in; (void)out_size; (void)d_ws; (void)ws_size;
    const float* x     = (const float*)d_in[0];
    const float* y     = (const float*)d_in[1];
    const float* theta = (const float*)d_in[2];
    float* out = (float*)d_out;

    const int Bx = in_sizes[0] / 4;  // 8192
    const int By = in_sizes[1] / 4;  // 8192

    if ((Bx % PBM) == 0 && (By % PBN) == 0) {
        const int nblk = (Bx / PBM) * (By / PBN);   // 64 * 32 = 2048
        qk_persist<<<dim3(nblk), dim3(256), 0, stream>>>(x, y, theta, out, Bx, By);
    } else if ((By % (BN * TJ)) == 0 && (Bx % BM) == 0) {
        dim3 grid(By / (BN * TJ), Bx / BM);
        qk_stream<<<grid, dim3(256), 0, stream>>>(x, y, theta, out, Bx, By);
    } else {
        dim3 grid(By / BN, Bx / BM);
        qk_stream<<<grid, dim3(256), 0, stream>>>(x, y, theta, out, Bx, By);
    }
}